// Round 7
// baseline (85.641 us; speedup 1.0000x reference)
//
#include <hip/hip_runtime.h>
#include <float.h>

#define NB 8
#define NC 64
#define NH 32
#define NW 32
#define NQ 8
#define NK 256
#define NROWS (NB*NC*NH*NW)      // 524288
#define TPB 256
#define RPB 1024                 // rows per vq_main block (one (b,c) plane)
#define NBLK2 (NROWS/RPB)        // 512
#define BIT_OFF 1
#define REC_OFF (1 + NROWS*NQ)

// ws layout (bytes):
//  g_breaks: double[64][256]     @ 0        (128 KiB)
//  g_segcb:  float [64][256][8]  @ 196608   (512 KiB)
//  g_segR:   float [64][256]     @ 720896   ( 64 KiB)
//  g_segBG:  double[64][256][2]  @ 786432   (256 KiB)
//  g_alpha:  double[64]          @ 1048576
//  g_m:      int[64]             @ 1049088
//  partial:  double[512]         @ 1049856
#define WS_BREAKS(ws) ((double*)(ws))
#define WS_SEGCB(ws)  ((float*)((char*)(ws) + 196608))
#define WS_SEGR(ws)   ((float*)((char*)(ws) + 720896))
#define WS_SEGBG(ws)  ((double*)((char*)(ws) + 786432))
#define WS_ALPHA(ws)  ((double*)((char*)(ws) + 1048576))
#define WS_M(ws)      ((int*)((char*)(ws) + 1049088))
#define WS_PART(ws)   ((double*)((char*)(ws) + 1049856))

// ---------------------------------------------------------------------------
// Kernel A (parallel interval method): one thread per codebook line.
// Line i wins on (L_i, U_i); L_i = max_{S_j>S_i} cross, U_i = min_{S_j<S_i}
// cross, cross(i,j) = (P_i-P_j)/(S_j-S_i). Fractions (d>0) compared by
// cross-multiplication; ONE f64 divide per alive line reproduces the walk's
// break bit-identically (same numerator/denominator operands).
// ---------------------------------------------------------------------------
__global__ __launch_bounds__(NK) void vq_envelope(
    const float* __restrict__ w_pre,
    const float* __restrict__ b_pre,
    const float* __restrict__ codebook,
    const float* __restrict__ w_after,
    const float* __restrict__ b_after,
    double* __restrict__ g_breaks,
    float* __restrict__ g_segcb,
    float* __restrict__ g_segR,
    double* __restrict__ g_segBG,
    double* __restrict__ g_alpha,
    int* __restrict__ g_m)
{
    __shared__ double2 s_PS[NK];                 // {P, S} per line
    __shared__ double  s_Ln[NK], s_Ld[NK];       // L fraction (num, den>0)
    __shared__ unsigned char s_hasL[NK], s_alive[NK];

    const int c = blockIdx.x;
    const int i = threadIdx.x;

    // channel-uniform weights + kl quadratic constants (same fma chains as R6)
    double wp[NQ], bp[NQ], wa[NQ];
    double sw2 = 0.0, swb = 0.0, sb2 = 0.0;
    #pragma unroll
    for (int q = 0; q < NQ; q++) {
        wp[q] = (double)w_pre[c*NQ + q];
        bp[q] = (double)b_pre[c*NQ + q];
        wa[q] = (double)w_after[c*NQ + q];
        sw2 = fma(wp[q], wp[q], sw2);
        swb = fma(wp[q], bp[q], swb);
        sb2 = fma(bp[q], bp[q], sb2);
    }
    const double ba = (double)b_after[c];

    // own line: P_i, S_i (identical op order to the verified walk kernel)
    double c2 = 0.0, A = 0.0, Bv = 0.0;
    #pragma unroll
    for (int q = 0; q < NQ; q++) {
        double cv = (double)codebook[i*NQ + q];
        c2 = fma(cv, cv, c2);
        A  = fma(wp[q], cv, A);
        Bv = fma(bp[q], cv, Bv);
    }
    const double Pi = c2 - 2.0*Bv;
    const double Si = -2.0*A;
    s_PS[i] = make_double2(Pi, Si);
    __syncthreads();

    // interval bounds as fractions; j runs uniformly -> LDS broadcast reads
    double nL = 0.0, dL = 0.0, nU = 0.0, dU = 0.0;
    bool hasL = false, hasU = false, dead = false;
    for (int j = 0; j < NK; j++) {
        const double2 ps = s_PS[j];
        if (j == i) continue;
        const double dS = ps.y - Si;             // S_j - S_i (exact)
        if (dS > 0.0) {                          // L side: cross = (Pi-Pj)/(Sj-Si)
            const double n = Pi - ps.x, d = dS;
            bool take = !hasL || (n*dL > nL*d);  // strict max; tie keeps first j
            if (take) { nL = n; dL = d; hasL = true; }
        } else if (dS < 0.0) {                   // U side
            const double n = ps.x - Pi, d = -dS;
            bool take = !hasU || (n*dU < nU*d);  // strict min
            if (take) { nU = n; dU = d; hasU = true; }
        } else {                                 // equal slopes: domination
            if (ps.x < Pi || (ps.x == Pi && j < i)) dead = true;
        }
    }
    bool alive = !dead;
    if (alive && hasL && hasU) alive = (nL*dU < nU*dL);   // L < U
    const double Lv = hasL ? (nL/dL) : -DBL_MAX;          // one div per line

    s_Ln[i] = nL; s_Ld[i] = dL;
    s_hasL[i] = hasL ? 1 : 0;
    s_alive[i] = alive ? 1 : 0;
    __syncthreads();

    // rank among alive lines by L ascending (tie: S desc, then index); total m
    int rank = 0, mtot = 0;
    for (int j = 0; j < NK; j++) {
        if (!s_alive[j]) continue;
        mtot++;
        if (j == i) continue;
        bool before;
        const bool jHas = (s_hasL[j] != 0);
        if (!jHas)       before = true;           // L_j = -inf
        else if (!hasL)  before = false;          // L_i = -inf
        else {
            const double a = s_Ln[j]*dL, b2 = nL*s_Ld[j];
            if (a < b2)      before = true;
            else if (a > b2) before = false;
            else {
                const double Sj = s_PS[j].y;
                before = (Sj > Si) || (Sj == Si && j < i);
            }
        }
        if (before) rank++;
    }

    if (alive) {
        if (rank > 0) g_breaks[c*NK + rank] = Lv;
        double R = ba;
        #pragma unroll
        for (int q = 0; q < NQ; q++) {
            const float cf = codebook[i*NQ + q];
            g_segcb[(c*NK + rank)*NQ + q] = cf;
            R = fma(wa[q], (double)cf, R);        // same chain as R6
        }
        g_segR[c*NK + rank] = (float)R;
        g_segBG[(c*NK + rank)*2 + 0] = Si + 2.0*swb;   // beta  == (-2A)+2swb
        g_segBG[(c*NK + rank)*2 + 1] = Pi + sb2;       // gamma == (c2-2Bv)+sb2
    }
    if (i == 0) {
        g_m[c] = mtot;
        g_alpha[c] = sw2;
    }
}

// ---------------------------------------------------------------------------
// Kernel B: 512 blocks, 1024 rows each (one (b,c) plane); 4 rows per thread.
// ---------------------------------------------------------------------------
__global__ __launch_bounds__(TPB) void vq_main(
    const float* __restrict__ x,
    const double* __restrict__ g_breaks,
    const float* __restrict__ g_segcb,
    const float* __restrict__ g_segR,
    const double* __restrict__ g_segBG,
    const double* __restrict__ g_alpha,
    const int* __restrict__ g_m,
    float* __restrict__ out,
    double* __restrict__ partial)
{
    __shared__ double s_brk[NK];
    __shared__ float  s_cb[NK][9];     // stride 9: conflict-light divergent reads
    __shared__ float  s_R[NK];
    __shared__ double s_bg[NK][2];
    __shared__ double s_alpha;
    __shared__ double s_part[TPB/64];

    const int tid = threadIdx.x;
    const int bc = blockIdx.x;         // = b*64 + c
    const int b = bc >> 6;
    const int c = bc & 63;
    const int rowbase = bc * RPB;

    const int m = g_m[c];
    if (tid == 0) s_alpha = g_alpha[c];
    if (tid < m) {
        s_brk[tid] = (tid == 0) ? -DBL_MAX : g_breaks[c*NK + tid];
        const float4* cb4 = (const float4*)(g_segcb + (c*NK + tid)*NQ);
        float4 c0 = cb4[0], c1 = cb4[1];
        s_cb[tid][0] = c0.x; s_cb[tid][1] = c0.y; s_cb[tid][2] = c0.z; s_cb[tid][3] = c0.w;
        s_cb[tid][4] = c1.x; s_cb[tid][5] = c1.y; s_cb[tid][6] = c1.z; s_cb[tid][7] = c1.w;
        s_R[tid] = g_segR[c*NK + tid];
        const double2 bg = *(const double2*)(g_segBG + (c*NK + tid)*2);
        s_bg[tid][0] = bg.x; s_bg[tid][1] = bg.y;
    }
    __syncthreads();

    const double alpha = s_alpha;
    const int bq0 = BIT_OFF + (b*512 + c*8)*1024;

    double ktot = 0.0;
    #pragma unroll
    for (int r = 0; r < 4; r++) {
        const int hw  = r*256 + tid;
        const int gid = rowbase + hw;
        const double xv = (double)x[gid];

        int lo = 0, hi = m - 1;
        while (lo < hi) {                       // block-uniform trip count
            int mid = (lo + hi + 1) >> 1;
            if (s_brk[mid] <= xv) lo = mid; else hi = mid - 1;
        }

        #pragma unroll
        for (int q = 0; q < NQ; q++)
            out[bq0 + q*1024 + hw] = s_cb[lo][q];
        out[REC_OFF + gid] = s_R[lo];

        ktot += fma(xv, fma(xv, alpha, s_bg[lo][0]), s_bg[lo][1]);
    }

    #pragma unroll
    for (int off = 32; off; off >>= 1)
        ktot += __shfl_down(ktot, off, 64);
    if ((tid & 63) == 0) s_part[tid >> 6] = ktot;
    __syncthreads();
    if (tid == 0)
        partial[blockIdx.x] = s_part[0] + s_part[1] + s_part[2] + s_part[3];
}

__global__ __launch_bounds__(TPB) void vq_fin(
    const double* __restrict__ partial,
    float* __restrict__ out)
{
    double s = 0.0;
    for (int i = threadIdx.x; i < NBLK2; i += TPB) s += partial[i];
    #pragma unroll
    for (int off = 32; off; off >>= 1)
        s += __shfl_down(s, off, 64);
    __shared__ double sp[TPB/64];
    if ((threadIdx.x & 63) == 0) sp[threadIdx.x >> 6] = s;
    __syncthreads();
    if (threadIdx.x == 0) {
        double m = (sp[0] + sp[1] + sp[2] + sp[3]) / (double)(NROWS * NQ);
        out[0] = (float)(1.25 * m);
    }
}

extern "C" void kernel_launch(void* const* d_in, const int* in_sizes, int n_in,
                              void* d_out, int out_size, void* d_ws, size_t ws_size,
                              hipStream_t stream) {
    const float* x        = (const float*)d_in[0];
    const float* w_pre    = (const float*)d_in[1];
    const float* b_pre    = (const float*)d_in[2];
    const float* codebook = (const float*)d_in[3];
    const float* w_after  = (const float*)d_in[4];
    const float* b_after  = (const float*)d_in[5];
    float* out = (float*)d_out;

    vq_envelope<<<NC, NK, 0, stream>>>(w_pre, b_pre, codebook, w_after, b_after,
                                       WS_BREAKS(d_ws), WS_SEGCB(d_ws),
                                       WS_SEGR(d_ws), WS_SEGBG(d_ws), WS_ALPHA(d_ws),
                                       WS_M(d_ws));
    vq_main<<<NBLK2, TPB, 0, stream>>>(x, WS_BREAKS(d_ws), WS_SEGCB(d_ws),
                                       WS_SEGR(d_ws), WS_SEGBG(d_ws), WS_ALPHA(d_ws),
                                       WS_M(d_ws), out, WS_PART(d_ws));
    vq_fin<<<1, TPB, 0, stream>>>(WS_PART(d_ws), out);
}

// Round 8
// 74.302 us; speedup vs baseline: 1.1526x; 1.1526x over previous
//
#include <hip/hip_runtime.h>
#include <float.h>

#define NB 8
#define NC 64
#define NH 32
#define NW 32
#define NQ 8
#define NK 256
#define NROWS (NB*NC*NH*NW)      // 524288
#define TPB 256
#define RPB 1024                 // rows per vq_main block (one (b,c) plane)
#define NBLK2 (NROWS/RPB)        // 512
#define BIT_OFF 1
#define REC_OFF (1 + NROWS*NQ)

// ws layout (bytes):
//  g_breaks: double[64][256]     @ 0        (128 KiB)
//  g_segcb:  float [64][256][8]  @ 196608   (512 KiB)
//  g_segR:   float [64][256]     @ 720896   ( 64 KiB)
//  g_segBG:  double[64][256][2]  @ 786432   (256 KiB)
//  g_alpha:  double[64]          @ 1048576
//  g_m:      int[64]             @ 1049088
//  partial:  double[512]         @ 1049856
#define WS_BREAKS(ws) ((double*)(ws))
#define WS_SEGCB(ws)  ((float*)((char*)(ws) + 196608))
#define WS_SEGR(ws)   ((float*)((char*)(ws) + 720896))
#define WS_SEGBG(ws)  ((double*)((char*)(ws) + 786432))
#define WS_ALPHA(ws)  ((double*)((char*)(ws) + 1048576))
#define WS_M(ws)      ((int*)((char*)(ws) + 1049088))
#define WS_PART(ws)   ((double*)((char*)(ws) + 1049856))

// ---------------------------------------------------------------------------
// Kernel A (parallel interval method, latency-tolerant): one thread per line.
// Interval: L_i = max_{S_j>S_i} (P_i-P_j)/(S_j-S_i), U_i = min_{S_j<S_i} ...;
// fractions compared by cross-mult (d>0), ONE divide per alive line -> breaks
// bit-identical to the verified serial walk. Segment order = S descending
// (envelope slope is strictly decreasing), so rank = count of alive S_j > S_i.
// j-loops batched 8-wide so LDS reads pipeline (8 outstanding b128s).
// ---------------------------------------------------------------------------
__global__ __launch_bounds__(NK) void vq_envelope(
    const float* __restrict__ w_pre,
    const float* __restrict__ b_pre,
    const float* __restrict__ codebook,
    const float* __restrict__ w_after,
    const float* __restrict__ b_after,
    double* __restrict__ g_breaks,
    float* __restrict__ g_segcb,
    float* __restrict__ g_segR,
    double* __restrict__ g_segBG,
    double* __restrict__ g_alpha,
    int* __restrict__ g_m)
{
    __shared__ double2 s_PS[NK];     // {P, S} per line
    __shared__ double  s_key[NK];    // alive ? S : -DBL_MAX

    const int c = blockIdx.x;
    const int i = threadIdx.x;

    // channel-uniform weights + kl quadratic constants (same fma chains)
    double wp[NQ], bp[NQ], wa[NQ];
    double sw2 = 0.0, swb = 0.0, sb2 = 0.0;
    #pragma unroll
    for (int q = 0; q < NQ; q++) {
        wp[q] = (double)w_pre[c*NQ + q];
        bp[q] = (double)b_pre[c*NQ + q];
        wa[q] = (double)w_after[c*NQ + q];
        sw2 = fma(wp[q], wp[q], sw2);
        swb = fma(wp[q], bp[q], swb);
        sb2 = fma(bp[q], bp[q], sb2);
    }
    const double ba = (double)b_after[c];

    // own line: P_i, S_i (identical op order to the verified kernels)
    double c2 = 0.0, A = 0.0, Bv = 0.0;
    #pragma unroll
    for (int q = 0; q < NQ; q++) {
        double cv = (double)codebook[i*NQ + q];
        c2 = fma(cv, cv, c2);
        A  = fma(wp[q], cv, A);
        Bv = fma(bp[q], cv, Bv);
    }
    const double Pi = c2 - 2.0*Bv;
    const double Si = -2.0*A;
    s_PS[i] = make_double2(Pi, Si);
    __syncthreads();

    // ---- pass 1: interval bounds, 8-wide batched LDS reads ----
    double nL = 0.0, dL = 0.0, nU = 0.0, dU = 0.0;  // has* <=> d* > 0
    bool dead = false;
    for (int jb = 0; jb < NK; jb += 8) {
        double2 ps[8];
        #pragma unroll
        for (int u = 0; u < 8; u++) ps[u] = s_PS[jb + u];
        #pragma unroll
        for (int u = 0; u < 8; u++) {
            const int j = jb + u;                   // j==i harmless (dS==0 path)
            const double dS = ps[u].y - Si;
            if (dS > 0.0) {                          // L side
                const double n = Pi - ps[u].x;
                if (dL == 0.0 || n*dL > nL*dS) { nL = n; dL = dS; }
            } else if (dS < 0.0) {                   // U side
                const double n = ps[u].x - Pi, d = -dS;
                if (dU == 0.0 || n*dU < nU*d) { nU = n; dU = d; }
            } else {
                if (ps[u].x < Pi || (ps[u].x == Pi && j < i)) dead = true;
            }
        }
    }
    bool alive = !dead;
    if (alive && dL > 0.0 && dU > 0.0) alive = (nL*dU < nU*dL);   // L < U
    const double Lv = (dL > 0.0) ? (nL/dL) : -DBL_MAX;  // one div per line

    s_key[i] = alive ? Si : -DBL_MAX;
    __syncthreads();

    // ---- pass 2: rank by S descending among alive (tie: lower index first) --
    int rank = 0, mtot = 0;
    for (int jb = 0; jb < NK; jb += 8) {
        double k8[8];
        #pragma unroll
        for (int u = 0; u < 8; u++) k8[u] = s_key[jb + u];
        #pragma unroll
        for (int u = 0; u < 8; u++) {
            const int j = jb + u;
            mtot += (k8[u] != -DBL_MAX) ? 1 : 0;
            if (k8[u] > Si || (k8[u] == Si && k8[u] != -DBL_MAX && j < i)) rank++;
        }
    }

    if (alive) {
        if (rank > 0) g_breaks[c*NK + rank] = Lv;
        double R = ba;
        #pragma unroll
        for (int q = 0; q < NQ; q++) {
            const float cf = codebook[i*NQ + q];
            g_segcb[(c*NK + rank)*NQ + q] = cf;
            R = fma(wa[q], (double)cf, R);           // same chain as before
        }
        g_segR[c*NK + rank] = (float)R;
        g_segBG[(c*NK + rank)*2 + 0] = Si + 2.0*swb;   // beta
        g_segBG[(c*NK + rank)*2 + 1] = Pi + sb2;       // gamma
    }
    if (i == 0) {
        g_m[c] = mtot;
        g_alpha[c] = sw2;
    }
}

// ---------------------------------------------------------------------------
// Kernel B: 512 blocks, 1024 rows each (one (b,c) plane); 4 rows per thread.
// ---------------------------------------------------------------------------
__global__ __launch_bounds__(TPB) void vq_main(
    const float* __restrict__ x,
    const double* __restrict__ g_breaks,
    const float* __restrict__ g_segcb,
    const float* __restrict__ g_segR,
    const double* __restrict__ g_segBG,
    const double* __restrict__ g_alpha,
    const int* __restrict__ g_m,
    float* __restrict__ out,
    double* __restrict__ partial)
{
    __shared__ double s_brk[NK];
    __shared__ float  s_cb[NK][9];     // stride 9: conflict-light divergent reads
    __shared__ float  s_R[NK];
    __shared__ double s_bg[NK][2];
    __shared__ double s_alpha;
    __shared__ double s_part[TPB/64];

    const int tid = threadIdx.x;
    const int bc = blockIdx.x;         // = b*64 + c
    const int b = bc >> 6;
    const int c = bc & 63;
    const int rowbase = bc * RPB;

    const int m = g_m[c];
    if (tid == 0) s_alpha = g_alpha[c];
    if (tid < m) {
        s_brk[tid] = (tid == 0) ? -DBL_MAX : g_breaks[c*NK + tid];
        const float4* cb4 = (const float4*)(g_segcb + (c*NK + tid)*NQ);
        float4 c0 = cb4[0], c1 = cb4[1];
        s_cb[tid][0] = c0.x; s_cb[tid][1] = c0.y; s_cb[tid][2] = c0.z; s_cb[tid][3] = c0.w;
        s_cb[tid][4] = c1.x; s_cb[tid][5] = c1.y; s_cb[tid][6] = c1.z; s_cb[tid][7] = c1.w;
        s_R[tid] = g_segR[c*NK + tid];
        const double2 bg = *(const double2*)(g_segBG + (c*NK + tid)*2);
        s_bg[tid][0] = bg.x; s_bg[tid][1] = bg.y;
    }
    __syncthreads();

    const double alpha = s_alpha;
    const int bq0 = BIT_OFF + (b*512 + c*8)*1024;

    double ktot = 0.0;
    #pragma unroll
    for (int r = 0; r < 4; r++) {
        const int hw  = r*256 + tid;
        const int gid = rowbase + hw;
        const double xv = (double)x[gid];

        int lo = 0, hi = m - 1;
        while (lo < hi) {                       // block-uniform trip count
            int mid = (lo + hi + 1) >> 1;
            if (s_brk[mid] <= xv) lo = mid; else hi = mid - 1;
        }

        #pragma unroll
        for (int q = 0; q < NQ; q++)
            out[bq0 + q*1024 + hw] = s_cb[lo][q];
        out[REC_OFF + gid] = s_R[lo];

        ktot += fma(xv, fma(xv, alpha, s_bg[lo][0]), s_bg[lo][1]);
    }

    #pragma unroll
    for (int off = 32; off; off >>= 1)
        ktot += __shfl_down(ktot, off, 64);
    if ((tid & 63) == 0) s_part[tid >> 6] = ktot;
    __syncthreads();
    if (tid == 0)
        partial[blockIdx.x] = s_part[0] + s_part[1] + s_part[2] + s_part[3];
}

__global__ __launch_bounds__(TPB) void vq_fin(
    const double* __restrict__ partial,
    float* __restrict__ out)
{
    double s = 0.0;
    for (int i = threadIdx.x; i < NBLK2; i += TPB) s += partial[i];
    #pragma unroll
    for (int off = 32; off; off >>= 1)
        s += __shfl_down(s, off, 64);
    __shared__ double sp[TPB/64];
    if ((threadIdx.x & 63) == 0) sp[threadIdx.x >> 6] = s;
    __syncthreads();
    if (threadIdx.x == 0) {
        double m = (sp[0] + sp[1] + sp[2] + sp[3]) / (double)(NROWS * NQ);
        out[0] = (float)(1.25 * m);
    }
}

extern "C" void kernel_launch(void* const* d_in, const int* in_sizes, int n_in,
                              void* d_out, int out_size, void* d_ws, size_t ws_size,
                              hipStream_t stream) {
    const float* x        = (const float*)d_in[0];
    const float* w_pre    = (const float*)d_in[1];
    const float* b_pre    = (const float*)d_in[2];
    const float* codebook = (const float*)d_in[3];
    const float* w_after  = (const float*)d_in[4];
    const float* b_after  = (const float*)d_in[5];
    float* out = (float*)d_out;

    vq_envelope<<<NC, NK, 0, stream>>>(w_pre, b_pre, codebook, w_after, b_after,
                                       WS_BREAKS(d_ws), WS_SEGCB(d_ws),
                                       WS_SEGR(d_ws), WS_SEGBG(d_ws), WS_ALPHA(d_ws),
                                       WS_M(d_ws));
    vq_main<<<NBLK2, TPB, 0, stream>>>(x, WS_BREAKS(d_ws), WS_SEGCB(d_ws),
                                       WS_SEGR(d_ws), WS_SEGBG(d_ws), WS_ALPHA(d_ws),
                                       WS_M(d_ws), out, WS_PART(d_ws));
    vq_fin<<<1, TPB, 0, stream>>>(WS_PART(d_ws), out);
}

// Round 9
// 44.655 us; speedup vs baseline: 1.9178x; 1.6639x over previous
//
#include <hip/hip_runtime.h>
#include <float.h>

#define NB 8
#define NC 64
#define NH 32
#define NW 32
#define NQ 8
#define NK 256
#define NROWS (NB*NC*NH*NW)      // 524288
#define TPB 256
#define RPB 1024                 // rows per vq_main block (one (b,c) plane)
#define NBLK2 (NROWS/RPB)        // 512
#define BIT_OFF 1
#define REC_OFF (1 + NROWS*NQ)

// ws layout (bytes):
//  g_breaks: double[64][256]     @ 0        (128 KiB)
//  g_segcb:  float [64][256][8]  @ 196608   (512 KiB)
//  g_segR:   float [64][256]     @ 720896   ( 64 KiB)
//  g_segBG:  double[64][256][2]  @ 786432   (256 KiB)
//  g_alpha:  double[64]          @ 1048576
//  g_m:      int[64]             @ 1049088
//  partial:  double[512]         @ 1049856
#define WS_BREAKS(ws) ((double*)(ws))
#define WS_SEGCB(ws)  ((float*)((char*)(ws) + 196608))
#define WS_SEGR(ws)   ((float*)((char*)(ws) + 720896))
#define WS_SEGBG(ws)  ((double*)((char*)(ws) + 786432))
#define WS_ALPHA(ws)  ((double*)((char*)(ws) + 1048576))
#define WS_M(ws)      ((int*)((char*)(ws) + 1049088))
#define WS_PART(ws)   ((double*)((char*)(ws) + 1049856))

// ---------------------------------------------------------------------------
// Kernel A: 1 block (1024 thr, 16 waves) per channel; 4 threads per line.
// Thread (sub,i), sub=t>>8, i=t&255: scans j in [64*sub, 64*sub+64).
// Partial L/U fractions merged in sub order => identical winner (and hence
// bit-identical nL/dL divide) as the verified serial fold. Segment order =
// S descending among alive lines; rank counted 4-way in parallel.
// ---------------------------------------------------------------------------
__global__ __launch_bounds__(1024) void vq_envelope(
    const float* __restrict__ w_pre,
    const float* __restrict__ b_pre,
    const float* __restrict__ codebook,
    const float* __restrict__ w_after,
    const float* __restrict__ b_after,
    double* __restrict__ g_breaks,
    float* __restrict__ g_segcb,
    float* __restrict__ g_segR,
    double* __restrict__ g_segBG,
    double* __restrict__ g_alpha,
    int* __restrict__ g_m)
{
    __shared__ double2 s_PS[NK];            // {P,S} per line
    __shared__ double  m_nL[4][NK], m_dL[4][NK];
    __shared__ double  m_nU[4][NK], m_dU[4][NK];
    __shared__ unsigned char m_dead[4][NK];
    __shared__ double  s_key[NK];           // alive ? S : -DBL_MAX
    __shared__ int     m_rank[4][NK];
    __shared__ int     s_mtotp[4];

    const int c   = blockIdx.x;
    const int t   = threadIdx.x;
    const int sub = t >> 8;
    const int i   = t & 255;

    // sub-0 threads: per-channel weights, kl constants, own line P,S
    double wp[NQ], bp[NQ], wa[NQ];
    double sw2 = 0.0, swb = 0.0, sb2 = 0.0, ba = 0.0;
    if (sub == 0) {
        #pragma unroll
        for (int q = 0; q < NQ; q++) {
            wp[q] = (double)w_pre[c*NQ + q];
            bp[q] = (double)b_pre[c*NQ + q];
            wa[q] = (double)w_after[c*NQ + q];
            sw2 = fma(wp[q], wp[q], sw2);
            swb = fma(wp[q], bp[q], swb);
            sb2 = fma(bp[q], bp[q], sb2);
        }
        ba = (double)b_after[c];
        double c2 = 0.0, A = 0.0, Bv = 0.0;
        #pragma unroll
        for (int q = 0; q < NQ; q++) {
            double cv = (double)codebook[i*NQ + q];
            c2 = fma(cv, cv, c2);
            A  = fma(wp[q], cv, A);
            Bv = fma(bp[q], cv, Bv);
        }
        s_PS[i] = make_double2(c2 - 2.0*Bv, -2.0*A);
    }
    __syncthreads();

    const double2 psi = s_PS[i];
    const double Pi = psi.x, Si = psi.y;

    // ---- pass 1: partial interval bounds over this sub's 64 j's ----
    double nL = 0.0, dL = 0.0, nU = 0.0, dU = 0.0;   // has* <=> d* > 0
    bool dead = false;
    const int j0 = sub * 64;
    for (int jb = 0; jb < 64; jb += 8) {
        double2 ps[8];
        #pragma unroll
        for (int u = 0; u < 8; u++) ps[u] = s_PS[j0 + jb + u];
        #pragma unroll
        for (int u = 0; u < 8; u++) {
            const int j = j0 + jb + u;               // j==i harmless (dS==0)
            const double dS = ps[u].y - Si;
            if (dS > 0.0) {                          // L side
                const double n = Pi - ps[u].x;
                if (dL == 0.0 || n*dL > nL*dS) { nL = n; dL = dS; }
            } else if (dS < 0.0) {                   // U side
                const double n = ps[u].x - Pi, d = -dS;
                if (dU == 0.0 || n*dU < nU*d) { nU = n; dU = d; }
            } else {
                if (ps[u].x < Pi || (ps[u].x == Pi && j < i)) dead = true;
            }
        }
    }
    m_nL[sub][i] = nL; m_dL[sub][i] = dL;
    m_nU[sub][i] = nU; m_dU[sub][i] = dU;
    m_dead[sub][i] = dead ? 1 : 0;
    __syncthreads();

    // ---- merge partials (sub order => first-j-wins preserved), alive, L ----
    bool alive = false;
    double Lv = -DBL_MAX;
    if (sub == 0) {
        double fnL = 0.0, fdL = 0.0, fnU = 0.0, fdU = 0.0;
        bool fdead = false;
        #pragma unroll
        for (int s2 = 0; s2 < 4; s2++) {
            const double n1 = m_nL[s2][i], d1 = m_dL[s2][i];
            if (d1 > 0.0 && (fdL == 0.0 || n1*fdL > fnL*d1)) { fnL = n1; fdL = d1; }
            const double n2 = m_nU[s2][i], d2 = m_dU[s2][i];
            if (d2 > 0.0 && (fdU == 0.0 || n2*fdU < fnU*d2)) { fnU = n2; fdU = d2; }
            fdead |= (m_dead[s2][i] != 0);
        }
        alive = !fdead;
        if (alive && fdL > 0.0 && fdU > 0.0) alive = (fnL*fdU < fnU*fdL);
        Lv = (fdL > 0.0) ? (fnL/fdL) : -DBL_MAX;     // bit-identical operands
        s_key[i] = alive ? Si : -DBL_MAX;
    }
    __syncthreads();

    // ---- rank partials: count alive S_j > S_i (tie: j<i) over 64 j's ----
    {
        int cnt = 0, mt = 0;
        for (int jb = 0; jb < 64; jb += 8) {
            double k8[8];
            #pragma unroll
            for (int u = 0; u < 8; u++) k8[u] = s_key[j0 + jb + u];
            #pragma unroll
            for (int u = 0; u < 8; u++) {
                const int j = j0 + jb + u;
                mt += (k8[u] != -DBL_MAX) ? 1 : 0;
                if (k8[u] > Si || (k8[u] == Si && k8[u] != -DBL_MAX && j < i)) cnt++;
            }
        }
        m_rank[sub][i] = cnt;
        if (i == 0) s_mtotp[sub] = mt;
    }
    __syncthreads();

    // ---- payload (sub-0 threads, one per line) ----
    if (sub == 0) {
        const int rank = m_rank[0][i] + m_rank[1][i] + m_rank[2][i] + m_rank[3][i];
        if (alive) {
            if (rank > 0) g_breaks[c*NK + rank] = Lv;
            double R = ba;
            #pragma unroll
            for (int q = 0; q < NQ; q++) {
                const float cf = codebook[i*NQ + q];
                g_segcb[(c*NK + rank)*NQ + q] = cf;
                R = fma(wa[q], (double)cf, R);       // same chain as verified
            }
            g_segR[c*NK + rank] = (float)R;
            g_segBG[(c*NK + rank)*2 + 0] = Si + 2.0*swb;   // beta
            g_segBG[(c*NK + rank)*2 + 1] = Pi + sb2;       // gamma
        }
        if (i == 0) {
            g_m[c] = s_mtotp[0] + s_mtotp[1] + s_mtotp[2] + s_mtotp[3];
            g_alpha[c] = sw2;
        }
    }
}

// ---------------------------------------------------------------------------
// Kernel B: 512 blocks, 1024 rows each (one (b,c) plane); 4 rows per thread.
// ---------------------------------------------------------------------------
__global__ __launch_bounds__(TPB) void vq_main(
    const float* __restrict__ x,
    const double* __restrict__ g_breaks,
    const float* __restrict__ g_segcb,
    const float* __restrict__ g_segR,
    const double* __restrict__ g_segBG,
    const double* __restrict__ g_alpha,
    const int* __restrict__ g_m,
    float* __restrict__ out,
    double* __restrict__ partial)
{
    __shared__ double s_brk[NK];
    __shared__ float  s_cb[NK][9];     // stride 9: conflict-light divergent reads
    __shared__ float  s_R[NK];
    __shared__ double s_bg[NK][2];
    __shared__ double s_alpha;
    __shared__ double s_part[TPB/64];

    const int tid = threadIdx.x;
    const int bc = blockIdx.x;         // = b*64 + c
    const int b = bc >> 6;
    const int c = bc & 63;
    const int rowbase = bc * RPB;

    const int m = g_m[c];
    if (tid == 0) s_alpha = g_alpha[c];
    if (tid < m) {
        s_brk[tid] = (tid == 0) ? -DBL_MAX : g_breaks[c*NK + tid];
        const float4* cb4 = (const float4*)(g_segcb + (c*NK + tid)*NQ);
        float4 c0 = cb4[0], c1 = cb4[1];
        s_cb[tid][0] = c0.x; s_cb[tid][1] = c0.y; s_cb[tid][2] = c0.z; s_cb[tid][3] = c0.w;
        s_cb[tid][4] = c1.x; s_cb[tid][5] = c1.y; s_cb[tid][6] = c1.z; s_cb[tid][7] = c1.w;
        s_R[tid] = g_segR[c*NK + tid];
        const double2 bg = *(const double2*)(g_segBG + (c*NK + tid)*2);
        s_bg[tid][0] = bg.x; s_bg[tid][1] = bg.y;
    }
    __syncthreads();

    const double alpha = s_alpha;
    const int bq0 = BIT_OFF + (b*512 + c*8)*1024;

    double ktot = 0.0;
    #pragma unroll
    for (int r = 0; r < 4; r++) {
        const int hw  = r*256 + tid;
        const int gid = rowbase + hw;
        const double xv = (double)x[gid];

        int lo = 0, hi = m - 1;
        while (lo < hi) {                       // block-uniform trip count
            int mid = (lo + hi + 1) >> 1;
            if (s_brk[mid] <= xv) lo = mid; else hi = mid - 1;
        }

        #pragma unroll
        for (int q = 0; q < NQ; q++)
            out[bq0 + q*1024 + hw] = s_cb[lo][q];
        out[REC_OFF + gid] = s_R[lo];

        ktot += fma(xv, fma(xv, alpha, s_bg[lo][0]), s_bg[lo][1]);
    }

    #pragma unroll
    for (int off = 32; off; off >>= 1)
        ktot += __shfl_down(ktot, off, 64);
    if ((tid & 63) == 0) s_part[tid >> 6] = ktot;
    __syncthreads();
    if (tid == 0)
        partial[blockIdx.x] = s_part[0] + s_part[1] + s_part[2] + s_part[3];
}

__global__ __launch_bounds__(TPB) void vq_fin(
    const double* __restrict__ partial,
    float* __restrict__ out)
{
    double s = 0.0;
    for (int i = threadIdx.x; i < NBLK2; i += TPB) s += partial[i];
    #pragma unroll
    for (int off = 32; off; off >>= 1)
        s += __shfl_down(s, off, 64);
    __shared__ double sp[TPB/64];
    if ((threadIdx.x & 63) == 0) sp[threadIdx.x >> 6] = s;
    __syncthreads();
    if (threadIdx.x == 0) {
        double m = (sp[0] + sp[1] + sp[2] + sp[3]) / (double)(NROWS * NQ);
        out[0] = (float)(1.25 * m);
    }
}

extern "C" void kernel_launch(void* const* d_in, const int* in_sizes, int n_in,
                              void* d_out, int out_size, void* d_ws, size_t ws_size,
                              hipStream_t stream) {
    const float* x        = (const float*)d_in[0];
    const float* w_pre    = (const float*)d_in[1];
    const float* b_pre    = (const float*)d_in[2];
    const float* codebook = (const float*)d_in[3];
    const float* w_after  = (const float*)d_in[4];
    const float* b_after  = (const float*)d_in[5];
    float* out = (float*)d_out;

    vq_envelope<<<NC, 1024, 0, stream>>>(w_pre, b_pre, codebook, w_after, b_after,
                                         WS_BREAKS(d_ws), WS_SEGCB(d_ws),
                                         WS_SEGR(d_ws), WS_SEGBG(d_ws), WS_ALPHA(d_ws),
                                         WS_M(d_ws));
    vq_main<<<NBLK2, TPB, 0, stream>>>(x, WS_BREAKS(d_ws), WS_SEGCB(d_ws),
                                       WS_SEGR(d_ws), WS_SEGBG(d_ws), WS_ALPHA(d_ws),
                                       WS_M(d_ws), out, WS_PART(d_ws));
    vq_fin<<<1, TPB, 0, stream>>>(WS_PART(d_ws), out);
}

// Round 10
// 25.840 us; speedup vs baseline: 3.3143x; 1.7281x over previous
//
#include <hip/hip_runtime.h>
#include <float.h>

#define NB 8
#define NC 64
#define NH 32
#define NW 32
#define NQ 8
#define NK 256
#define NROWS (NB*NC*NH*NW)      // 524288
#define TPB 256
#define RPB 1024                 // rows per vq_main block (one (b,c) plane)
#define NBLK2 (NROWS/RPB)        // 512
#define BIT_OFF 1
#define REC_OFF (1 + NROWS*NQ)

// ws layout (bytes):
//  g_breaks: double[64][256]     @ 0        (128 KiB)
//  g_segcb:  float [64][256][8]  @ 196608   (512 KiB)
//  g_segR:   float [64][256]     @ 720896   ( 64 KiB)
//  g_segBG:  double[64][256][2]  @ 786432   (256 KiB)
//  g_alpha:  double[64]          @ 1048576
//  g_m:      int[64]             @ 1049088
//  partial:  double[512]         @ 1049856
#define WS_BREAKS(ws) ((double*)(ws))
#define WS_SEGCB(ws)  ((float*)((char*)(ws) + 196608))
#define WS_SEGR(ws)   ((float*)((char*)(ws) + 720896))
#define WS_SEGBG(ws)  ((double*)((char*)(ws) + 786432))
#define WS_ALPHA(ws)  ((double*)((char*)(ws) + 1048576))
#define WS_M(ws)      ((int*)((char*)(ws) + 1049088))
#define WS_PART(ws)   ((double*)((char*)(ws) + 1049856))

// ---------------------------------------------------------------------------
// Kernel A: one block (256 thr = 4 waves) per channel. The serial envelope
// walk (R6's verified step code, 14us for the full walk) is split across 4
// waves by x-interval: wave w covers [M_w, M_{w+1}), starting from the
// winner at M_w (parallel argmin reduce) and recording crossings < M_{w+1}.
// Crossings from the same cur use identical operands => stitched break list
// is bit-identical to the full serial walk (exact ties at M_w: measure zero).
// ---------------------------------------------------------------------------
__global__ __launch_bounds__(256) void vq_envelope(
    const float* __restrict__ w_pre,
    const float* __restrict__ b_pre,
    const float* __restrict__ codebook,
    const float* __restrict__ w_after,
    const float* __restrict__ b_after,
    double* __restrict__ g_breaks,
    float* __restrict__ g_segcb,
    float* __restrict__ g_segR,
    double* __restrict__ g_segBG,
    double* __restrict__ g_alpha,
    int* __restrict__ g_m)
{
    __shared__ double2 s_PS[NK];        // {P,S} per line
    __shared__ float   s_cbf[NK][NQ];   // raw f32 codebook rows
    __shared__ double  l_brk[4][NK];    // per-wave crossing lists
    __shared__ short   l_win[4][NK];
    __shared__ int     s_p[4];          // per-wave entry counts

    const int c    = blockIdx.x;
    const int t    = threadIdx.x;
    const int w    = t >> 6;
    const int lane = t & 63;

    // channel-uniform weights + kl constants (same fma chains as verified)
    double wp[NQ], bp[NQ], wa[NQ];
    double sw2 = 0.0, swb = 0.0, sb2 = 0.0;
    #pragma unroll
    for (int q = 0; q < NQ; q++) {
        wp[q] = (double)w_pre[c*NQ + q];
        bp[q] = (double)b_pre[c*NQ + q];
        wa[q] = (double)w_after[c*NQ + q];
        sw2 = fma(wp[q], wp[q], sw2);
        swb = fma(wp[q], bp[q], swb);
        sb2 = fma(bp[q], bp[q], sb2);
    }
    const double ba = (double)b_after[c];

    // stage: thread t computes line t's P,S (identical op order)
    {
        double c2 = 0.0, A = 0.0, Bv = 0.0;
        #pragma unroll
        for (int q = 0; q < NQ; q++) {
            const float cf = codebook[t*NQ + q];
            s_cbf[t][q] = cf;
            const double cv = (double)cf;
            c2 = fma(cv, cv, c2);
            A  = fma(wp[q], cv, A);
            Bv = fma(bp[q], cv, Bv);
        }
        s_PS[t] = make_double2(c2 - 2.0*Bv, -2.0*A);
    }
    __syncthreads();

    // per-wave register copy: lane owns lines 4*lane..4*lane+3
    double P[4], S[4];
    #pragma unroll
    for (int i = 0; i < 4; i++) {
        const double2 ps = s_PS[4*lane + i];
        P[i] = ps.x; S[i] = ps.y;
    }

    // x-interval bounds for this wave
    const double Ms  = (w == 1) ? -1.0 : (w == 2) ? 0.0125 : 1.0;  // start (w>0)
    const double Mhi = (w == 0) ? -1.0 : (w == 1) ? 0.0125
                     : (w == 2) ? 1.0  : DBL_MAX;                   // stop

    // start winner for this wave
    int cur;
    if (w == 0) {
        // winner at x=-inf: max S, tie min P, tie min k (R6 code)
        double bs = S[0], bP = P[0];
        int bk = 4*lane;
        #pragma unroll
        for (int i = 1; i < 4; i++) {
            const int k = 4*lane + i;
            if (S[i] > bs || (S[i] == bs && (P[i] < bP || (P[i] == bP && k < bk)))) {
                bs = S[i]; bP = P[i]; bk = k;
            }
        }
        #pragma unroll
        for (int off = 32; off; off >>= 1) {
            double os = __shfl_xor(bs, off, 64);
            double oP = __shfl_xor(bP, off, 64);
            int    ok = __shfl_xor(bk, off, 64);
            if (os > bs || (os == bs && (oP < bP || (oP == bP && ok < bk)))) {
                bs = os; bP = oP; bk = ok;
            }
        }
        cur = bk;
    } else {
        // winner at x=Ms: min P + Ms*S, tie min k
        double bd = fma(Ms, S[0], P[0]);
        int bk = 4*lane;
        #pragma unroll
        for (int i = 1; i < 4; i++) {
            const double d = fma(Ms, S[i], P[i]);
            const int k = 4*lane + i;
            if (d < bd || (d == bd && k < bk)) { bd = d; bk = k; }
        }
        #pragma unroll
        for (int off = 32; off; off >>= 1) {
            double od = __shfl_xor(bd, off, 64);
            int    ok = __shfl_xor(bk, off, 64);
            if (od < bd || (od == bd && ok < bk)) { bd = od; bk = ok; }
        }
        cur = bk;
    }

    int p = 0;
    if (w == 0) { if (lane == 0) l_win[0][0] = (short)cur; p = 1; }

    // walk (R6's verified step), record crossings in [*, Mhi)
    while (p < NK) {
        const double2 psi = s_PS[cur];       // wave-uniform broadcast
        const double Pi = psi.x, Si = psi.y;

        double cx = DBL_MAX, cs = 0.0;
        int cj = NK;
        #pragma unroll
        for (int i = 0; i < 4; i++) {
            const int k = 4*lane + i;
            if (S[i] < Si) {
                const double tt = (P[i] - Pi) / (Si - S[i]);
                if (tt < cx || (tt == cx && (S[i] < cs || (S[i] == cs && k < cj)))) {
                    cx = tt; cs = S[i]; cj = k;
                }
            }
        }
        #pragma unroll
        for (int off = 32; off; off >>= 1) {
            double ox = __shfl_xor(cx, off, 64);
            double os = __shfl_xor(cs, off, 64);
            int    oj = __shfl_xor(cj, off, 64);
            if (ox < cx || (ox == cx && (os < cs || (os == cs && oj < cj)))) {
                cx = ox; cs = os; cj = oj;
            }
        }
        if (cx >= Mhi) break;                // covers DBL_MAX (no crossing) too
        if (lane == 0) {
            l_brk[w][p] = cx;
            l_win[w][p] = (short)cj;
        }
        cur = cj;
        p++;
    }
    if (lane == 0) s_p[w] = p;
    __syncthreads();

    // prefix offsets + payload (thread t handles global rank t)
    const int o1 = s_p[0];
    const int o2 = o1 + s_p[1];
    const int o3 = o2 + s_p[2];
    const int m  = o3 + s_p[3];

    if (t < m) {
        int w2, s2;
        if      (t < o1) { w2 = 0; s2 = t; }
        else if (t < o2) { w2 = 1; s2 = t - o1; }
        else if (t < o3) { w2 = 2; s2 = t - o2; }
        else             { w2 = 3; s2 = t - o3; }
        const int j = l_win[w2][s2];
        if (t > 0) g_breaks[c*NK + t] = l_brk[w2][s2];
        const double2 ps = s_PS[j];
        double R = ba;
        #pragma unroll
        for (int q = 0; q < NQ; q++) {
            const float cf = s_cbf[j][q];
            g_segcb[(c*NK + t)*NQ + q] = cf;
            R = fma(wa[q], (double)cf, R);   // same chain as verified
        }
        g_segR[c*NK + t] = (float)R;
        g_segBG[(c*NK + t)*2 + 0] = ps.y + 2.0*swb;   // beta
        g_segBG[(c*NK + t)*2 + 1] = ps.x + sb2;       // gamma
    }
    if (t == 0) {
        g_m[c] = m;
        g_alpha[c] = sw2;
    }
}

// ---------------------------------------------------------------------------
// Kernel B: 512 blocks, 1024 rows each (one (b,c) plane); 4 rows per thread.
// ---------------------------------------------------------------------------
__global__ __launch_bounds__(TPB) void vq_main(
    const float* __restrict__ x,
    const double* __restrict__ g_breaks,
    const float* __restrict__ g_segcb,
    const float* __restrict__ g_segR,
    const double* __restrict__ g_segBG,
    const double* __restrict__ g_alpha,
    const int* __restrict__ g_m,
    float* __restrict__ out,
    double* __restrict__ partial)
{
    __shared__ double s_brk[NK];
    __shared__ float  s_cb[NK][9];     // stride 9: conflict-light divergent reads
    __shared__ float  s_R[NK];
    __shared__ double s_bg[NK][2];
    __shared__ double s_alpha;
    __shared__ double s_part[TPB/64];

    const int tid = threadIdx.x;
    const int bc = blockIdx.x;         // = b*64 + c
    const int b = bc >> 6;
    const int c = bc & 63;
    const int rowbase = bc * RPB;

    const int m = g_m[c];
    if (tid == 0) s_alpha = g_alpha[c];
    if (tid < m) {
        s_brk[tid] = (tid == 0) ? -DBL_MAX : g_breaks[c*NK + tid];
        const float4* cb4 = (const float4*)(g_segcb + (c*NK + tid)*NQ);
        float4 c0 = cb4[0], c1 = cb4[1];
        s_cb[tid][0] = c0.x; s_cb[tid][1] = c0.y; s_cb[tid][2] = c0.z; s_cb[tid][3] = c0.w;
        s_cb[tid][4] = c1.x; s_cb[tid][5] = c1.y; s_cb[tid][6] = c1.z; s_cb[tid][7] = c1.w;
        s_R[tid] = g_segR[c*NK + tid];
        const double2 bg = *(const double2*)(g_segBG + (c*NK + tid)*2);
        s_bg[tid][0] = bg.x; s_bg[tid][1] = bg.y;
    }
    __syncthreads();

    const double alpha = s_alpha;
    const int bq0 = BIT_OFF + (b*512 + c*8)*1024;

    double ktot = 0.0;
    #pragma unroll
    for (int r = 0; r < 4; r++) {
        const int hw  = r*256 + tid;
        const int gid = rowbase + hw;
        const double xv = (double)x[gid];

        int lo = 0, hi = m - 1;
        while (lo < hi) {                       // block-uniform trip count
            int mid = (lo + hi + 1) >> 1;
            if (s_brk[mid] <= xv) lo = mid; else hi = mid - 1;
        }

        #pragma unroll
        for (int q = 0; q < NQ; q++)
            out[bq0 + q*1024 + hw] = s_cb[lo][q];
        out[REC_OFF + gid] = s_R[lo];

        ktot += fma(xv, fma(xv, alpha, s_bg[lo][0]), s_bg[lo][1]);
    }

    #pragma unroll
    for (int off = 32; off; off >>= 1)
        ktot += __shfl_down(ktot, off, 64);
    if ((tid & 63) == 0) s_part[tid >> 6] = ktot;
    __syncthreads();
    if (tid == 0)
        partial[blockIdx.x] = s_part[0] + s_part[1] + s_part[2] + s_part[3];
}

__global__ __launch_bounds__(TPB) void vq_fin(
    const double* __restrict__ partial,
    float* __restrict__ out)
{
    double s = 0.0;
    for (int i = threadIdx.x; i < NBLK2; i += TPB) s += partial[i];
    #pragma unroll
    for (int off = 32; off; off >>= 1)
        s += __shfl_down(s, off, 64);
    __shared__ double sp[TPB/64];
    if ((threadIdx.x & 63) == 0) sp[threadIdx.x >> 6] = s;
    __syncthreads();
    if (threadIdx.x == 0) {
        double m = (sp[0] + sp[1] + sp[2] + sp[3]) / (double)(NROWS * NQ);
        out[0] = (float)(1.25 * m);
    }
}

extern "C" void kernel_launch(void* const* d_in, const int* in_sizes, int n_in,
                              void* d_out, int out_size, void* d_ws, size_t ws_size,
                              hipStream_t stream) {
    const float* x        = (const float*)d_in[0];
    const float* w_pre    = (const float*)d_in[1];
    const float* b_pre    = (const float*)d_in[2];
    const float* codebook = (const float*)d_in[3];
    const float* w_after  = (const float*)d_in[4];
    const float* b_after  = (const float*)d_in[5];
    float* out = (float*)d_out;

    vq_envelope<<<NC, 256, 0, stream>>>(w_pre, b_pre, codebook, w_after, b_after,
                                        WS_BREAKS(d_ws), WS_SEGCB(d_ws),
                                        WS_SEGR(d_ws), WS_SEGBG(d_ws), WS_ALPHA(d_ws),
                                        WS_M(d_ws));
    vq_main<<<NBLK2, TPB, 0, stream>>>(x, WS_BREAKS(d_ws), WS_SEGCB(d_ws),
                                       WS_SEGR(d_ws), WS_SEGBG(d_ws), WS_ALPHA(d_ws),
                                       WS_M(d_ws), out, WS_PART(d_ws));
    vq_fin<<<1, TPB, 0, stream>>>(WS_PART(d_ws), out);
}

// Round 11
// 24.430 us; speedup vs baseline: 3.5056x; 1.0577x over previous
//
#include <hip/hip_runtime.h>
#include <float.h>

#define NB 8
#define NC 64
#define NH 32
#define NW 32
#define NQ 8
#define NK 256
#define NROWS (NB*NC*NH*NW)      // 524288
#define TPB 256
#define RPB 1024                 // rows per vq_main block (one (b,c) plane)
#define NBLK2 (NROWS/RPB)        // 512
#define BIT_OFF 1
#define REC_OFF (1 + NROWS*NQ)
#define NWV 16                   // walk waves per channel

// ws layout (bytes):
//  g_breaks: double[64][256]     @ 0        (128 KiB)
//  g_segcb:  float [64][256][8]  @ 196608   (512 KiB)
//  g_segR:   float [64][256]     @ 720896   ( 64 KiB)
//  g_segBG:  double[64][256][2]  @ 786432   (256 KiB)
//  g_alpha:  double[64]          @ 1048576
//  g_m:      int[64]             @ 1049088
//  partial:  double[512]         @ 1049856
#define WS_BREAKS(ws) ((double*)(ws))
#define WS_SEGCB(ws)  ((float*)((char*)(ws) + 196608))
#define WS_SEGR(ws)   ((float*)((char*)(ws) + 720896))
#define WS_SEGBG(ws)  ((double*)((char*)(ws) + 786432))
#define WS_ALPHA(ws)  ((double*)((char*)(ws) + 1048576))
#define WS_M(ws)      ((int*)((char*)(ws) + 1049088))
#define WS_PART(ws)   ((double*)((char*)(ws) + 1049856))

// Cauchy quantiles tan(pi*(w/16 - 1/2)), w = 0..15 (w=0 unused)
__device__ __constant__ double c_tanq[16] = {
    0.0,
    -5.027339492125846, -2.414213562373095, -1.496605762665489, -1.0,
    -0.6681786379192989, -0.41421356237309503, -0.198912367379658, 0.0,
    0.198912367379658, 0.41421356237309503, 0.6681786379192989, 1.0,
    1.496605762665489, 2.414213562373095, 5.027339492125846 };

// ---------------------------------------------------------------------------
// Kernel A: one block (1024 thr = 16 waves) per channel. Serial envelope walk
// (R10's verified step code) split across 16 waves by x-interval, with split
// points at per-channel Cauchy quantiles m0 + gamma*tan(pi(w/16-1/2)) where
// m0 = -cov(P,S)/var(S), gamma = sqrt(residvar(P)/var(S)) — the natural
// center/scale of crossing positions x* = -dP/dS. Stitched list semantics
// identical to R10 (start winner at M_w, record crossings < M_{w+1}).
// ---------------------------------------------------------------------------
__global__ __launch_bounds__(1024) void vq_envelope(
    const float* __restrict__ w_pre,
    const float* __restrict__ b_pre,
    const float* __restrict__ codebook,
    const float* __restrict__ w_after,
    const float* __restrict__ b_after,
    double* __restrict__ g_breaks,
    float* __restrict__ g_segcb,
    float* __restrict__ g_segR,
    double* __restrict__ g_segBG,
    double* __restrict__ g_alpha,
    int* __restrict__ g_m)
{
    __shared__ double2 s_PS[NK];          // {P,S} per line
    __shared__ float   s_cbf[NK][NQ];     // raw f32 codebook rows
    __shared__ double  l_brk[NWV][NK];    // per-wave crossing lists (32 KiB)
    __shared__ short   l_win[NWV][NK];
    __shared__ int     s_p[NWV];
    __shared__ int     s_off[NWV + 1];
    __shared__ double  s_red[4][5];       // staging-wave partial sums
    __shared__ double  s_M[NWV];          // split points (s_M[0] unused)

    const int c    = blockIdx.x;
    const int t    = threadIdx.x;
    const int w    = t >> 6;              // wave id 0..15
    const int lane = t & 63;

    // staging threads (t<256): channel weights, kl constants, own line P,S
    double wa[NQ];
    double sw2 = 0.0, swb = 0.0, sb2 = 0.0, ba = 0.0;
    if (t < NK) {
        double wp[NQ], bp[NQ];
        #pragma unroll
        for (int q = 0; q < NQ; q++) {
            wp[q] = (double)w_pre[c*NQ + q];
            bp[q] = (double)b_pre[c*NQ + q];
            wa[q] = (double)w_after[c*NQ + q];
            sw2 = fma(wp[q], wp[q], sw2);
            swb = fma(wp[q], bp[q], swb);
            sb2 = fma(bp[q], bp[q], sb2);
        }
        ba = (double)b_after[c];
        double c2 = 0.0, A = 0.0, Bv = 0.0;
        #pragma unroll
        for (int q = 0; q < NQ; q++) {
            const float cf = codebook[t*NQ + q];
            s_cbf[t][q] = cf;
            const double cv = (double)cf;
            c2 = fma(cv, cv, c2);
            A  = fma(wp[q], cv, A);
            Bv = fma(bp[q], cv, Bv);
        }
        const double Pi = c2 - 2.0*Bv;
        const double Si = -2.0*A;
        s_PS[t] = make_double2(Pi, Si);

        // partial sums for m0/gamma (5 reductions over 4 staging waves)
        double r0 = Pi, r1 = Pi*Pi, r2 = Si, r3 = Si*Si, r4 = Pi*Si;
        #pragma unroll
        for (int off = 32; off; off >>= 1) {
            r0 += __shfl_xor(r0, off, 64);
            r1 += __shfl_xor(r1, off, 64);
            r2 += __shfl_xor(r2, off, 64);
            r3 += __shfl_xor(r3, off, 64);
            r4 += __shfl_xor(r4, off, 64);
        }
        if (lane == 0) {
            s_red[w][0] = r0; s_red[w][1] = r1; s_red[w][2] = r2;
            s_red[w][3] = r3; s_red[w][4] = r4;
        }
    }
    __syncthreads();

    if (t == 0) {
        double sP  = s_red[0][0] + s_red[1][0] + s_red[2][0] + s_red[3][0];
        double sP2 = s_red[0][1] + s_red[1][1] + s_red[2][1] + s_red[3][1];
        double sS  = s_red[0][2] + s_red[1][2] + s_red[2][2] + s_red[3][2];
        double sS2 = s_red[0][3] + s_red[1][3] + s_red[2][3] + s_red[3][3];
        double sPS = s_red[0][4] + s_red[1][4] + s_red[2][4] + s_red[3][4];
        const double n = (double)NK;
        const double mP = sP/n, mS = sS/n;
        const double vP = fmax(sP2/n - mP*mP, 0.0);
        const double vS = fmax(sS2/n - mS*mS, 1e-300);
        const double cv = sPS/n - mP*mS;
        const double m0 = -cv / vS;
        const double gm = sqrt(fmax(vP - cv*cv/vS, 0.0) / vS) + 1e-300;
        #pragma unroll
        for (int i = 1; i < NWV; i++) s_M[i] = fma(gm, c_tanq[i], m0);
    }
    __syncthreads();

    // per-wave register copy: lane owns lines 4*lane..4*lane+3
    double P[4], S[4];
    #pragma unroll
    for (int i = 0; i < 4; i++) {
        const double2 ps = s_PS[4*lane + i];
        P[i] = ps.x; S[i] = ps.y;
    }

    const double Mhi = (w == NWV-1) ? DBL_MAX : s_M[w+1];

    // start winner for this wave (R10's verified code)
    int cur;
    if (w == 0) {
        double bs = S[0], bP = P[0];
        int bk = 4*lane;
        #pragma unroll
        for (int i = 1; i < 4; i++) {
            const int k = 4*lane + i;
            if (S[i] > bs || (S[i] == bs && (P[i] < bP || (P[i] == bP && k < bk)))) {
                bs = S[i]; bP = P[i]; bk = k;
            }
        }
        #pragma unroll
        for (int off = 32; off; off >>= 1) {
            double os = __shfl_xor(bs, off, 64);
            double oP = __shfl_xor(bP, off, 64);
            int    ok = __shfl_xor(bk, off, 64);
            if (os > bs || (os == bs && (oP < bP || (oP == bP && ok < bk)))) {
                bs = os; bP = oP; bk = ok;
            }
        }
        cur = bk;
    } else {
        const double Ms = s_M[w];
        double bd = fma(Ms, S[0], P[0]);
        int bk = 4*lane;
        #pragma unroll
        for (int i = 1; i < 4; i++) {
            const double d = fma(Ms, S[i], P[i]);
            const int k = 4*lane + i;
            if (d < bd || (d == bd && k < bk)) { bd = d; bk = k; }
        }
        #pragma unroll
        for (int off = 32; off; off >>= 1) {
            double od = __shfl_xor(bd, off, 64);
            int    ok = __shfl_xor(bk, off, 64);
            if (od < bd || (od == bd && ok < bk)) { bd = od; bk = ok; }
        }
        cur = bk;
    }

    int p = 0;
    if (w == 0) { if (lane == 0) l_win[0][0] = (short)cur; p = 1; }

    // walk (R10's verified step), record crossings < Mhi
    while (p < NK) {
        const double2 psi = s_PS[cur];       // wave-uniform broadcast
        const double Pi = psi.x, Si = psi.y;

        double cx = DBL_MAX, cs = 0.0;
        int cj = NK;
        #pragma unroll
        for (int i = 0; i < 4; i++) {
            const int k = 4*lane + i;
            if (S[i] < Si) {
                const double tt = (P[i] - Pi) / (Si - S[i]);
                if (tt < cx || (tt == cx && (S[i] < cs || (S[i] == cs && k < cj)))) {
                    cx = tt; cs = S[i]; cj = k;
                }
            }
        }
        #pragma unroll
        for (int off = 32; off; off >>= 1) {
            double ox = __shfl_xor(cx, off, 64);
            double os = __shfl_xor(cs, off, 64);
            int    oj = __shfl_xor(cj, off, 64);
            if (ox < cx || (ox == cx && (os < cs || (os == cs && oj < cj)))) {
                cx = ox; cs = os; cj = oj;
            }
        }
        if (cx >= Mhi) break;                // also covers DBL_MAX (no crossing)
        if (lane == 0) {
            l_brk[w][p] = cx;
            l_win[w][p] = (short)cj;
        }
        cur = cj;
        p++;
    }
    if (lane == 0) s_p[w] = p;
    __syncthreads();

    if (t == 0) {
        s_off[0] = 0;
        #pragma unroll
        for (int i = 0; i < NWV; i++) s_off[i+1] = s_off[i] + s_p[i];
        g_m[c] = s_off[NWV];
        g_alpha[c] = sw2;
    }
    __syncthreads();

    // payload: thread t handles global rank t (t < m <= 256)
    const int m = s_off[NWV];
    if (t < m) {
        int w2 = 0;
        while (t >= s_off[w2+1]) w2++;
        const int s2 = t - s_off[w2];
        const int j = l_win[w2][s2];
        if (t > 0) g_breaks[c*NK + t] = l_brk[w2][s2];
        const double2 ps = s_PS[j];
        double R = ba;
        #pragma unroll
        for (int q = 0; q < NQ; q++) {
            const float cf = s_cbf[j][q];
            g_segcb[(c*NK + t)*NQ + q] = cf;
            R = fma(wa[q], (double)cf, R);   // same chain as verified
        }
        g_segR[c*NK + t] = (float)R;
        g_segBG[(c*NK + t)*2 + 0] = ps.y + 2.0*swb;   // beta
        g_segBG[(c*NK + t)*2 + 1] = ps.x + sb2;       // gamma
    }
}

// ---------------------------------------------------------------------------
// Kernel B: 512 blocks, 1024 rows each (one (b,c) plane); 4 rows per thread.
// ---------------------------------------------------------------------------
__global__ __launch_bounds__(TPB) void vq_main(
    const float* __restrict__ x,
    const double* __restrict__ g_breaks,
    const float* __restrict__ g_segcb,
    const float* __restrict__ g_segR,
    const double* __restrict__ g_segBG,
    const double* __restrict__ g_alpha,
    const int* __restrict__ g_m,
    float* __restrict__ out,
    double* __restrict__ partial)
{
    __shared__ double s_brk[NK];
    __shared__ float  s_cb[NK][9];     // stride 9: conflict-light divergent reads
    __shared__ float  s_R[NK];
    __shared__ double s_bg[NK][2];
    __shared__ double s_alpha;
    __shared__ double s_part[TPB/64];

    const int tid = threadIdx.x;
    const int bc = blockIdx.x;         // = b*64 + c
    const int b = bc >> 6;
    const int c = bc & 63;
    const int rowbase = bc * RPB;

    const int m = g_m[c];
    if (tid == 0) s_alpha = g_alpha[c];
    if (tid < m) {
        s_brk[tid] = (tid == 0) ? -DBL_MAX : g_breaks[c*NK + tid];
        const float4* cb4 = (const float4*)(g_segcb + (c*NK + tid)*NQ);
        float4 c0 = cb4[0], c1 = cb4[1];
        s_cb[tid][0] = c0.x; s_cb[tid][1] = c0.y; s_cb[tid][2] = c0.z; s_cb[tid][3] = c0.w;
        s_cb[tid][4] = c1.x; s_cb[tid][5] = c1.y; s_cb[tid][6] = c1.z; s_cb[tid][7] = c1.w;
        s_R[tid] = g_segR[c*NK + tid];
        const double2 bg = *(const double2*)(g_segBG + (c*NK + tid)*2);
        s_bg[tid][0] = bg.x; s_bg[tid][1] = bg.y;
    }
    __syncthreads();

    const double alpha = s_alpha;
    const int bq0 = BIT_OFF + (b*512 + c*8)*1024;

    double ktot = 0.0;
    #pragma unroll
    for (int r = 0; r < 4; r++) {
        const int hw  = r*256 + tid;
        const int gid = rowbase + hw;
        const double xv = (double)x[gid];

        int lo = 0, hi = m - 1;
        while (lo < hi) {                       // block-uniform trip count
            int mid = (lo + hi + 1) >> 1;
            if (s_brk[mid] <= xv) lo = mid; else hi = mid - 1;
        }

        #pragma unroll
        for (int q = 0; q < NQ; q++)
            out[bq0 + q*1024 + hw] = s_cb[lo][q];
        out[REC_OFF + gid] = s_R[lo];

        ktot += fma(xv, fma(xv, alpha, s_bg[lo][0]), s_bg[lo][1]);
    }

    #pragma unroll
    for (int off = 32; off; off >>= 1)
        ktot += __shfl_down(ktot, off, 64);
    if ((tid & 63) == 0) s_part[tid >> 6] = ktot;
    __syncthreads();
    if (tid == 0)
        partial[blockIdx.x] = s_part[0] + s_part[1] + s_part[2] + s_part[3];
}

__global__ __launch_bounds__(TPB) void vq_fin(
    const double* __restrict__ partial,
    float* __restrict__ out)
{
    double s = 0.0;
    for (int i = threadIdx.x; i < NBLK2; i += TPB) s += partial[i];
    #pragma unroll
    for (int off = 32; off; off >>= 1)
        s += __shfl_down(s, off, 64);
    __shared__ double sp[TPB/64];
    if ((threadIdx.x & 63) == 0) sp[threadIdx.x >> 6] = s;
    __syncthreads();
    if (threadIdx.x == 0) {
        double m = (sp[0] + sp[1] + sp[2] + sp[3]) / (double)(NROWS * NQ);
        out[0] = (float)(1.25 * m);
    }
}

extern "C" void kernel_launch(void* const* d_in, const int* in_sizes, int n_in,
                              void* d_out, int out_size, void* d_ws, size_t ws_size,
                              hipStream_t stream) {
    const float* x        = (const float*)d_in[0];
    const float* w_pre    = (const float*)d_in[1];
    const float* b_pre    = (const float*)d_in[2];
    const float* codebook = (const float*)d_in[3];
    const float* w_after  = (const float*)d_in[4];
    const float* b_after  = (const float*)d_in[5];
    float* out = (float*)d_out;

    vq_envelope<<<NC, 1024, 0, stream>>>(w_pre, b_pre, codebook, w_after, b_after,
                                         WS_BREAKS(d_ws), WS_SEGCB(d_ws),
                                         WS_SEGR(d_ws), WS_SEGBG(d_ws), WS_ALPHA(d_ws),
                                         WS_M(d_ws));
    vq_main<<<NBLK2, TPB, 0, stream>>>(x, WS_BREAKS(d_ws), WS_SEGCB(d_ws),
                                       WS_SEGR(d_ws), WS_SEGBG(d_ws), WS_ALPHA(d_ws),
                                       WS_M(d_ws), out, WS_PART(d_ws));
    vq_fin<<<1, TPB, 0, stream>>>(WS_PART(d_ws), out);
}

// Round 12
// 22.920 us; speedup vs baseline: 3.7366x; 1.0659x over previous
//
#include <hip/hip_runtime.h>
#include <float.h>

#define NB 8
#define NC 64
#define NQ 8
#define NK 256
#define NROWS 524288
#define TPB 256
#define RPB 1024                 // rows per vq_main block
#define NBLK2 512
#define BIT_OFF 1
#define REC_OFF (1 + NROWS*NQ)
#define NWV 16                   // x-intervals per channel
#define SLOT 96                  // list slots per interval

// ws layout (bytes), total 899072 < proven 1.07 MB:
//  g_brk f64 [64][16][96] @ 0       (786432)
//  g_win u8  [64][16][96] @ 786432  ( 98304)
//  g_cnt s16 [64][16]     @ 884736  (  2048)
//  g_M   f64 [64][16]     @ 886784  (  8192)
//  part  f64 [512]        @ 894976  (  4096)
#define WS_BRK(ws)  ((double*)(ws))
#define WS_WIN(ws)  ((unsigned char*)((char*)(ws) + 786432))
#define WS_CNT(ws)  ((short*)((char*)(ws) + 884736))
#define WS_M(ws)    ((double*)((char*)(ws) + 886784))
#define WS_PART(ws) ((double*)((char*)(ws) + 894976))

// Cauchy quantiles tan(pi*(w/16 - 1/2)); index 0 unused as a start
__device__ __constant__ double c_tanq[17] = {
    0.0,
    -5.027339492125846, -2.414213562373095, -1.496605762665489, -1.0,
    -0.6681786379192989, -0.41421356237309503, -0.198912367379658, 0.0,
    0.198912367379658, 0.41421356237309503, 0.6681786379192989, 1.0,
    1.496605762665489, 2.414213562373095, 5.027339492125846, 0.0 };

// ---------------------------------------------------------------------------
// Kernel A: 1024 blocks x 64 threads; block (c,w) = one wave on its own SIMD.
// Redundantly computes channel stats (deterministic => identical M across the
// channel's 16 blocks), then walks the envelope over [M_w, M_{w+1}) with the
// verified R10/R11 step code. Writes its list to fixed per-(c,w) slots.
// ---------------------------------------------------------------------------
__global__ __launch_bounds__(64) void vq_envelope(
    const float* __restrict__ w_pre,
    const float* __restrict__ b_pre,
    const float* __restrict__ codebook,
    double* __restrict__ g_brk,
    unsigned char* __restrict__ g_win,
    short* __restrict__ g_cnt,
    double* __restrict__ g_M)
{
    __shared__ double2 s_PS[NK];

    const int bid  = blockIdx.x;
    const int c    = bid >> 4;
    const int w    = bid & 15;
    const int lane = threadIdx.x;

    double wp[NQ], bp[NQ];
    #pragma unroll
    for (int q = 0; q < NQ; q++) {
        wp[q] = (double)w_pre[c*NQ + q];
        bp[q] = (double)b_pre[c*NQ + q];
    }

    // own 4 lines: P,S (verified op order) + stats partials
    double P[4], S[4];
    double r0 = 0.0, r1 = 0.0, r2 = 0.0, r3 = 0.0, r4 = 0.0;
    #pragma unroll
    for (int i = 0; i < 4; i++) {
        const int k = 4*lane + i;
        double c2 = 0.0, A = 0.0, Bv = 0.0;
        #pragma unroll
        for (int q = 0; q < NQ; q++) {
            const double cv = (double)codebook[k*NQ + q];
            c2 = fma(cv, cv, c2);
            A  = fma(wp[q], cv, A);
            Bv = fma(bp[q], cv, Bv);
        }
        P[i] = c2 - 2.0*Bv;
        S[i] = -2.0*A;
        s_PS[k] = make_double2(P[i], S[i]);
        r0 += P[i]; r1 += P[i]*P[i]; r2 += S[i]; r3 += S[i]*S[i]; r4 += P[i]*S[i];
    }
    __syncthreads();

    #pragma unroll
    for (int off = 32; off; off >>= 1) {
        r0 += __shfl_xor(r0, off, 64);
        r1 += __shfl_xor(r1, off, 64);
        r2 += __shfl_xor(r2, off, 64);
        r3 += __shfl_xor(r3, off, 64);
        r4 += __shfl_xor(r4, off, 64);
    }
    const double n  = 256.0;
    const double mP = r0/n, mS = r2/n;
    const double vP = fmax(r1/n - mP*mP, 0.0);
    const double vS = fmax(r3/n - mS*mS, 1e-300);
    const double cv = r4/n - mP*mS;
    const double m0 = -cv / vS;
    const double gm = sqrt(fmax(vP - cv*cv/vS, 0.0) / vS) + 1e-300;
    const double Ms  = fma(gm, c_tanq[w], m0);
    const double Mhi = (w == NWV-1) ? DBL_MAX : fma(gm, c_tanq[w+1], m0);
    if (lane == 0) g_M[c*NWV + w] = (w == 0) ? -DBL_MAX : Ms;

    // start winner (verified R10/R11 code)
    int cur;
    if (w == 0) {
        double bs = S[0], bP = P[0];
        int bk = 4*lane;
        #pragma unroll
        for (int i = 1; i < 4; i++) {
            const int k = 4*lane + i;
            if (S[i] > bs || (S[i] == bs && (P[i] < bP || (P[i] == bP && k < bk)))) {
                bs = S[i]; bP = P[i]; bk = k;
            }
        }
        #pragma unroll
        for (int off = 32; off; off >>= 1) {
            double os = __shfl_xor(bs, off, 64);
            double oP = __shfl_xor(bP, off, 64);
            int    ok = __shfl_xor(bk, off, 64);
            if (os > bs || (os == bs && (oP < bP || (oP == bP && ok < bk)))) {
                bs = os; bP = oP; bk = ok;
            }
        }
        cur = bk;
    } else {
        double bd = fma(Ms, S[0], P[0]);
        int bk = 4*lane;
        #pragma unroll
        for (int i = 1; i < 4; i++) {
            const double d = fma(Ms, S[i], P[i]);
            const int k = 4*lane + i;
            if (d < bd || (d == bd && k < bk)) { bd = d; bk = k; }
        }
        #pragma unroll
        for (int off = 32; off; off >>= 1) {
            double od = __shfl_xor(bd, off, 64);
            int    ok = __shfl_xor(bk, off, 64);
            if (od < bd || (od == bd && ok < bk)) { bd = od; bk = ok; }
        }
        cur = bk;
    }

    const int gb = (c*NWV + w) * SLOT;
    if (lane == 0) g_win[gb] = (unsigned char)cur;
    int p = 1;
    bool trunc = false;

    while (true) {
        const double2 psi = s_PS[cur];       // wave-uniform broadcast
        const double Pi = psi.x, Si = psi.y;

        double cx = DBL_MAX, cs = 0.0;
        int cj = NK;
        #pragma unroll
        for (int i = 0; i < 4; i++) {
            const int k = 4*lane + i;
            if (S[i] < Si) {
                const double tt = (P[i] - Pi) / (Si - S[i]);
                if (tt < cx || (tt == cx && (S[i] < cs || (S[i] == cs && k < cj)))) {
                    cx = tt; cs = S[i]; cj = k;
                }
            }
        }
        #pragma unroll
        for (int off = 32; off; off >>= 1) {
            double ox = __shfl_xor(cx, off, 64);
            double os = __shfl_xor(cs, off, 64);
            int    oj = __shfl_xor(cj, off, 64);
            if (ox < cx || (ox == cx && (os < cs || (os == cs && oj < cj)))) {
                cx = ox; cs = os; cj = oj;
            }
        }
        if (cx >= Mhi) break;                // includes DBL_MAX (no crossing)
        if (p >= SLOT) { trunc = true; break; }
        if (lane == 0) {
            g_brk[gb + p] = cx;
            g_win[gb + p] = (unsigned char)cj;
        }
        cur = cj;
        p++;
    }
    if (lane == 0) g_cnt[c*NWV + w] = trunc ? (short)-1 : (short)p;
}

// ---------------------------------------------------------------------------
// Kernel B: 512 blocks x 256 thr, 1024 rows each. Rebuilds per-code payload
// locally; two-level search (interval, then in-list binary search). Fallback:
// exact 256-code f64 scan if any interval list truncated (prob ~ 0).
// ---------------------------------------------------------------------------
__global__ __launch_bounds__(TPB) void vq_main(
    const float* __restrict__ x,
    const float* __restrict__ w_pre,
    const float* __restrict__ b_pre,
    const float* __restrict__ codebook,
    const float* __restrict__ w_after,
    const float* __restrict__ b_after,
    const double* __restrict__ g_brk,
    const unsigned char* __restrict__ g_win,
    const short* __restrict__ g_cnt,
    const double* __restrict__ g_M,
    float* __restrict__ out,
    double* __restrict__ partial)
{
    __shared__ float  s_cb[NK][9];          // stride 9: conflict-light
    __shared__ float  s_R[NK];
    __shared__ double s_bg[NK][2];          // {beta, gamma} per code
    __shared__ double s_brk[NWV*SLOT];      // 12 KB
    __shared__ unsigned char s_win[NWV*SLOT];
    __shared__ short  s_cnt[NWV];
    __shared__ double s_M[NWV];
    __shared__ int    s_bad;
    __shared__ double s_part[TPB/64];

    const int tid = threadIdx.x;
    const int bc = blockIdx.x;
    const int b = bc >> 6;
    const int c = bc & 63;
    const int rowbase = bc * RPB;

    // uniform channel constants (scalar-load'd by compiler)
    double wp[NQ], bp[NQ], wa[NQ];
    double sw2 = 0.0, swb = 0.0, sb2 = 0.0;
    #pragma unroll
    for (int q = 0; q < NQ; q++) {
        wp[q] = (double)w_pre[c*NQ + q];
        bp[q] = (double)b_pre[c*NQ + q];
        wa[q] = (double)w_after[c*NQ + q];
        sw2 = fma(wp[q], wp[q], sw2);
        swb = fma(wp[q], bp[q], swb);
        sb2 = fma(bp[q], bp[q], sb2);
    }
    const double ba = (double)b_after[c];
    const double alpha = sw2;

    if (tid == 0) s_bad = 0;

    // per-code payload (verified fma chains)
    {
        const float4* cb4 = (const float4*)(codebook + tid*NQ);
        const float4 c0 = cb4[0], c1 = cb4[1];
        float cf[NQ] = {c0.x, c0.y, c0.z, c0.w, c1.x, c1.y, c1.z, c1.w};
        double c2 = 0.0, A = 0.0, Bv = 0.0, R = ba;
        #pragma unroll
        for (int q = 0; q < NQ; q++) {
            s_cb[tid][q] = cf[q];
            const double cvv = (double)cf[q];
            c2 = fma(cvv, cvv, c2);
            A  = fma(wp[q], cvv, A);
            Bv = fma(bp[q], cvv, Bv);
            R  = fma(wa[q], cvv, R);
        }
        const double Pv = c2 - 2.0*Bv;
        const double Sv = -2.0*A;
        s_R[tid] = (float)R;
        s_bg[tid][0] = Sv + 2.0*swb;        // beta
        s_bg[tid][1] = Pv + sb2;            // gamma
    }
    // stage lists (slot 0 of each wave -> -inf break)
    #pragma unroll
    for (int it = 0; it < (NWV*SLOT)/TPB; it++) {
        const int idx = it*TPB + tid;
        const double v = g_brk[c*(NWV*SLOT) + idx];
        s_brk[idx] = ((idx % SLOT) == 0) ? -DBL_MAX : v;
        s_win[idx] = g_win[c*(NWV*SLOT) + idx];
    }
    if (tid < NWV) {
        const short cv = g_cnt[c*NWV + tid];
        s_cnt[tid] = cv;
        if (cv < 0) s_bad = 1;              // benign race (all write 1)
        s_M[tid] = g_M[c*NWV + tid];
    }
    __syncthreads();
    const bool bad = (s_bad != 0);          // block-uniform

    const int bq0 = BIT_OFF + (b*512 + c*8)*1024;
    double ktot = 0.0;

    #pragma unroll
    for (int r = 0; r < 4; r++) {
        const int hw  = r*256 + tid;
        const int gid = rowbase + hw;
        const double xv = (double)x[gid];

        int j;
        if (!bad) {
            int w = 0;
            #pragma unroll
            for (int i = 1; i < NWV; i++) w = (s_M[i] <= xv) ? i : w;
            const int base = w*SLOT;
            int lo = 0, hi = (int)s_cnt[w] - 1;
            while (lo < hi) {
                const int mid = (lo + hi + 1) >> 1;
                if (s_brk[base + mid] <= xv) lo = mid; else hi = mid - 1;
            }
            j = (int)s_win[base + lo];
        } else {
            // exact scan: argmin of fma(x,beta,gamma) == shifted distance
            double bd = DBL_MAX; j = 0;
            for (int k = 0; k < NK; k++) {
                const double d = fma(xv, s_bg[k][0], s_bg[k][1]);
                if (d < bd) { bd = d; j = k; }
            }
        }

        #pragma unroll
        for (int q = 0; q < NQ; q++)
            out[bq0 + q*1024 + hw] = s_cb[j][q];
        out[REC_OFF + gid] = s_R[j];

        ktot += fma(xv, fma(xv, alpha, s_bg[j][0]), s_bg[j][1]);
    }

    #pragma unroll
    for (int off = 32; off; off >>= 1)
        ktot += __shfl_down(ktot, off, 64);
    if ((tid & 63) == 0) s_part[tid >> 6] = ktot;
    __syncthreads();
    if (tid == 0)
        partial[blockIdx.x] = s_part[0] + s_part[1] + s_part[2] + s_part[3];
}

__global__ __launch_bounds__(TPB) void vq_fin(
    const double* __restrict__ partial,
    float* __restrict__ out)
{
    double s = 0.0;
    for (int i = threadIdx.x; i < NBLK2; i += TPB) s += partial[i];
    #pragma unroll
    for (int off = 32; off; off >>= 1)
        s += __shfl_down(s, off, 64);
    __shared__ double sp[TPB/64];
    if ((threadIdx.x & 63) == 0) sp[threadIdx.x >> 6] = s;
    __syncthreads();
    if (threadIdx.x == 0) {
        double m = (sp[0] + sp[1] + sp[2] + sp[3]) / (double)(NROWS * NQ);
        out[0] = (float)(1.25 * m);
    }
}

extern "C" void kernel_launch(void* const* d_in, const int* in_sizes, int n_in,
                              void* d_out, int out_size, void* d_ws, size_t ws_size,
                              hipStream_t stream) {
    const float* x        = (const float*)d_in[0];
    const float* w_pre    = (const float*)d_in[1];
    const float* b_pre    = (const float*)d_in[2];
    const float* codebook = (const float*)d_in[3];
    const float* w_after  = (const float*)d_in[4];
    const float* b_after  = (const float*)d_in[5];
    float* out = (float*)d_out;

    vq_envelope<<<NC*NWV, 64, 0, stream>>>(w_pre, b_pre, codebook,
                                           WS_BRK(d_ws), WS_WIN(d_ws),
                                           WS_CNT(d_ws), WS_M(d_ws));
    vq_main<<<NBLK2, TPB, 0, stream>>>(x, w_pre, b_pre, codebook, w_after, b_after,
                                       WS_BRK(d_ws), WS_WIN(d_ws), WS_CNT(d_ws),
                                       WS_M(d_ws), out, WS_PART(d_ws));
    vq_fin<<<1, TPB, 0, stream>>>(WS_PART(d_ws), out);
}